// Round 1
// 486.242 us; speedup vs baseline: 1.0431x; 1.0431x over previous
//
#include <hip/hip_runtime.h>
#include <hip/hip_bf16.h>
#include <math.h>

// Problem constants (from reference)
#define B_ 4
#define S_ 2048
#define D_ 2048
#define H_ 4096
#define M_ (B_*S_)   // 8192 rows for both GEMMs

// Segmented recurrence: 16 segments x 128 steps, 48-step warmup.
#define SEG 128
#define WARM 48
#define P_ (S_/SEG)   // 16

typedef __bf16 bf16x8 __attribute__((ext_vector_type(8)));
typedef float f32x4 __attribute__((ext_vector_type(4)));

__device__ __forceinline__ float bf2f(unsigned short v) {
    union { unsigned u; float f; } x; x.u = ((unsigned)v) << 16; return x.f;
}
__device__ __forceinline__ unsigned short f2bf(float f) {
    union { float f; unsigned u; } x; x.f = f;
    unsigned u = x.u;
    unsigned r = (u + 0x7fffu + ((u >> 16) & 1u)) >> 16;  // RNE
    return (unsigned short)r;
}

__device__ __forceinline__ float fast_exp2(float x) {
#if __has_builtin(__builtin_amdgcn_exp2f)
    return __builtin_amdgcn_exp2f(x);
#else
    return __builtin_exp2f(x);
#endif
}
__device__ __forceinline__ float fast_rcp(float x) {
    return __builtin_amdgcn_rcpf(x);
}

// ---------------- fp32 -> bf16 conversion (8 elems/thread) ----------------
__global__ void cvt_f32_bf16(const float* __restrict__ in,
                             unsigned short* __restrict__ out, int n) {
    int i = (blockIdx.x * blockDim.x + threadIdx.x) * 8;
    if (i >= n) return;
    float4 a = *(const float4*)(in + i);
    float4 b = *(const float4*)(in + i + 4);
    ushort4 o0; o0.x = f2bf(a.x); o0.y = f2bf(a.y); o0.z = f2bf(a.z); o0.w = f2bf(a.w);
    ushort4 o1; o1.x = f2bf(b.x); o1.y = f2bf(b.y); o1.z = f2bf(b.z); o1.w = f2bf(b.w);
    *(ushort4*)(out + i) = o0;
    *(ushort4*)(out + i + 4) = o1;
}

// ---------------- async global->LDS 16B copy ----------------
__device__ __forceinline__ void async_cp16(const unsigned short* g, unsigned short* l) {
    __builtin_amdgcn_global_load_lds(
        (__attribute__((address_space(1))) void*)g,
        (__attribute__((address_space(3))) void*)l,
        16, 0, 0);
}

// Raw barrier with compiler-only memory fence (NO vmcnt(0) drain — that drain
// is the whole point of this schedule: counted vmcnt keeps loads in flight).
__device__ __forceinline__ void fence_bar() {
    asm volatile("" ::: "memory");
    __builtin_amdgcn_s_barrier();
    asm volatile("" ::: "memory");
}

template<int N>
__device__ __forceinline__ void wait_vmcnt() {
    if constexpr (N == 0)      asm volatile("s_waitcnt vmcnt(0)" ::: "memory");
    else if constexpr (N == 4) asm volatile("s_waitcnt vmcnt(4)" ::: "memory");
    else if constexpr (N == 6) asm volatile("s_waitcnt vmcnt(6)" ::: "memory");
}

// ---------------- 256x256 8-phase GEMM (B^T layout) ----------------
// C[m,n] = sum_k A[m,k]*Bw[n,k] + bias[n]
// LDS: [buf][mat(A/B)][khalf][256 rows x 32 shorts] = 4 x 32KB = 128 KiB.
// Half-tile g: tau=g>>2, mat=g&1, kh=(g>>1)&1. Each half = 16KB = 2x16B/thread.
// Staging stream runs 5 halves ahead of consumption -> steady-state vmcnt(6)
// (3 half-tiles in flight), never vmcnt(0) in the main loop.
// T2 swizzle: logical byte Y stored at Y ^ (((Y>>7)&3)<<4) (row bits[2:1] into
// byte bits[5:4]); gload_lds writes linearly so the SOURCE address carries the
// inverse permutation; ds_read applies the same XOR (involution).

__device__ __forceinline__
void stage_half(int g, int G, unsigned short (&lds)[2][2][2][8192],
                const unsigned short* Asrc, const unsigned short* Bsrc,
                int K, int sdst)
{
    if (g >= G) return;
    const int tau = g >> 2;
    const int mat = g & 1;
    const int kh  = (g >> 1) & 1;
    const unsigned short* src = (mat ? Bsrc : Asrc) + (size_t)tau * 64 + kh * 32;
    unsigned short* dst = &lds[tau & 1][mat][kh][sdst];
    async_cp16(src, dst);
    async_cp16(src + (size_t)128 * K, dst + 4096);
}

__device__ __forceinline__
void mfma16(const bf16x8* a, const bf16x8* b, f32x4 (*acc)[4]) {
#pragma unroll
    for (int i = 0; i < 4; ++i)
#pragma unroll
        for (int j = 0; j < 4; ++j)
            acc[i][j] = __builtin_amdgcn_mfma_f32_16x16x32_bf16(
                a[i], b[j], acc[i][j], 0, 0, 0);
}

// One K-tile (BK=64) = 4 phases. Phase p: ds_read frags || issue 1 half-tile
// prefetch (g = 4t+p+5) -> barrier -> setprio(1) 16 MFMA setprio(0) -> barrier.
// vmcnt placed before the pre-MFMA barrier of phases 1 and 3:
//   P1 wait validates this tile's kh1 regions (read at P2/P3),
//   P3 wait validates next tile's kh0 regions (read at its P0/P1).
// Same-buffer overwrite (P3 stages tile t+2 A-kh0) is published-safe: its last
// reader is this tile's P1, two barriers earlier.
template<int BUF, int VP1, int VP3>
__device__ __forceinline__
void do_tile(int t, int G, unsigned short (&lds)[2][2][2][8192],
             const unsigned short* Asrc, const unsigned short* Bsrc, int K,
             int sdst, int aoff, int boff, f32x4 (*acc)[4])
{
    const int g0 = 4 * t + 5;
    bf16x8 a[4], b[4];

    // ---- Phase 0: k-slice 0, M-frags 0-3 (B ks0 loaded, reused in P1) ----
#pragma unroll
    for (int j = 0; j < 4; ++j)
        b[j] = *(const bf16x8*)(&lds[BUF][1][0][boff + j * 512]);
#pragma unroll
    for (int i = 0; i < 4; ++i)
        a[i] = *(const bf16x8*)(&lds[BUF][0][0][aoff + i * 512]);
    stage_half(g0 + 0, G, lds, Asrc, Bsrc, K, sdst);
    fence_bar();
    __builtin_amdgcn_s_setprio(1);
    mfma16(a, b, acc);
    __builtin_amdgcn_s_setprio(0);
    fence_bar();

    // ---- Phase 1: k-slice 0, M-frags 4-7 ----
#pragma unroll
    for (int i = 0; i < 4; ++i)
        a[i] = *(const bf16x8*)(&lds[BUF][0][0][aoff + (i + 4) * 512]);
    stage_half(g0 + 1, G, lds, Asrc, Bsrc, K, sdst);
    wait_vmcnt<VP1>();
    fence_bar();
    __builtin_amdgcn_s_setprio(1);
    mfma16(a, b, acc + 4);
    __builtin_amdgcn_s_setprio(0);
    fence_bar();

    // ---- Phase 2: k-slice 1, M-frags 0-3 ----
#pragma unroll
    for (int j = 0; j < 4; ++j)
        b[j] = *(const bf16x8*)(&lds[BUF][1][1][boff + j * 512]);
#pragma unroll
    for (int i = 0; i < 4; ++i)
        a[i] = *(const bf16x8*)(&lds[BUF][0][1][aoff + i * 512]);
    stage_half(g0 + 2, G, lds, Asrc, Bsrc, K, sdst);
    fence_bar();
    __builtin_amdgcn_s_setprio(1);
    mfma16(a, b, acc);
    __builtin_amdgcn_s_setprio(0);
    fence_bar();

    // ---- Phase 3: k-slice 1, M-frags 4-7 ----
#pragma unroll
    for (int i = 0; i < 4; ++i)
        a[i] = *(const bf16x8*)(&lds[BUF][0][1][aoff + (i + 4) * 512]);
    stage_half(g0 + 3, G, lds, Asrc, Bsrc, K, sdst);
    if constexpr (VP3 >= 0) wait_vmcnt<VP3>();
    fence_bar();
    __builtin_amdgcn_s_setprio(1);
    mfma16(a, b, acc + 4);
    __builtin_amdgcn_s_setprio(0);
    fence_bar();
}

template<bool OUT_BF16>
__device__ __forceinline__
void gemm256_body(const unsigned short* __restrict__ A,
                  const unsigned short* __restrict__ Bw,
                  const float* __restrict__ bias,
                  unsigned short* __restrict__ outB,
                  float* __restrict__ outF,
                  int M, int N, int K)
{
    __shared__ __align__(16) unsigned short lds[2][2][2][8192];  // 128 KiB

    const int tid  = threadIdx.x;
    const int lane = tid & 63;
    const int wave = tid >> 6;
    const int wm = wave >> 2;          // 0..1: 128-row half of C-tile
    const int wn = wave & 3;           // 0..3: 64-col slice of C-tile
    const int row0 = blockIdx.y * 256;
    const int col0 = blockIdx.x * 256;
    const int NT = K >> 6;             // K/64 (even: 32 or 64)
    const int G  = NT << 2;

    // staging: thread's linear LDS slot -> inverse-swizzled global source col
    const int srow = tid >> 2;                                  // 0..127 (+128 for j=1)
    const int scol = ((tid & 3) ^ ((tid >> 3) & 3)) * 8;        // inverse st-swizzle
    const unsigned short* Asrc = A  + (size_t)(row0 + srow) * K + scol;
    const unsigned short* Bsrc = Bw + (size_t)(col0 + srow) * K + scol;
    const int sdst = tid * 8;

    // ds_read fragment offsets (swizzled; row bits[2:1] == laneM bits[2:1])
    const int laneM = lane & 15;
    const int laneK = (lane >> 4) * 8;
    const int swz   = ((laneM >> 1) & 3) << 3;
    const int aoff  = (((wm * 128 + laneM) * 32 + laneK)) ^ swz;
    const int boff  = (((wn * 64  + laneM) * 32 + laneK)) ^ swz;

    f32x4 acc[8][4];
#pragma unroll
    for (int i = 0; i < 8; ++i)
#pragma unroll
        for (int j = 0; j < 4; ++j)
            acc[i][j] = (f32x4){0.f, 0.f, 0.f, 0.f};

    // prologue: issue tile0 halves (g0-3) + tile1 A-kh0 (g4); vmcnt(6) retires
    // g0,g1 (tile0 kh0 A+B) leaving 3 halves in flight -> steady state.
    stage_half(0, G, lds, Asrc, Bsrc, K, sdst);
    stage_half(1, G, lds, Asrc, Bsrc, K, sdst);
    stage_half(2, G, lds, Asrc, Bsrc, K, sdst);
    stage_half(3, G, lds, Asrc, Bsrc, K, sdst);
    stage_half(4, G, lds, Asrc, Bsrc, K, sdst);
    wait_vmcnt<6>();
    fence_bar();

    int t = 0;
    for (; t < NT - 2; t += 2) {
        do_tile<0, 6, 6>(t,     G, lds, Asrc, Bsrc, K, sdst, aoff, boff, acc);
        do_tile<1, 6, 6>(t + 1, G, lds, Asrc, Bsrc, K, sdst, aoff, boff, acc);
    }
    // tail: staging stream caps at G -> drain 6 -> 4 -> 0
    do_tile<0, 6, 4>(NT - 2, G, lds, Asrc, Bsrc, K, sdst, aoff, boff, acc);
    do_tile<1, 0, -1>(NT - 1, G, lds, Asrc, Bsrc, K, sdst, aoff, boff, acc);

    // epilogue: C/D layout (verified m89/m91): m-row = (lane>>4)*4 + rr, n-col = lane&15
    const int rQ = (lane >> 4) * 4;
#pragma unroll
    for (int j = 0; j < 4; ++j) {
        const int n = col0 + wn * 64 + j * 16 + laneM;
        const float bv = bias[n];
#pragma unroll
        for (int i = 0; i < 8; ++i) {
#pragma unroll
            for (int rr = 0; rr < 4; ++rr) {
                const int m = row0 + wm * 128 + i * 16 + rQ + rr;
                const float v = acc[i][j][rr] + bv;
                if (OUT_BF16) outB[(size_t)m * N + n] = f2bf(v);
                else          outF[(size_t)m * N + n] = v;
            }
        }
    }
}

__global__ __launch_bounds__(512, 2)
void gemm_u(const unsigned short* __restrict__ A, const unsigned short* __restrict__ Bw,
            const float* __restrict__ bias, unsigned short* __restrict__ outB,
            int M, int N, int K) {
    gemm256_body<true>(A, Bw, bias, outB, nullptr, M, N, K);
}
__global__ __launch_bounds__(512, 2)
void gemm_y(const unsigned short* __restrict__ A, const unsigned short* __restrict__ Bw,
            const float* __restrict__ bias, float* __restrict__ outF,
            int M, int N, int K) {
    gemm256_body<false>(A, Bw, bias, nullptr, outF, M, N, K);
}

// ---------------- segmented-parallel tanh recurrence ----------------
__global__ __launch_bounds__(256)
void recur_seg(const unsigned short* __restrict__ u,
               const float* __restrict__ gamma,
               const float* __restrict__ beta,
               unsigned short* __restrict__ st)
{
    const int tid = blockIdx.x * 256 + threadIdx.x;   // [0, P_*B_*H_)
    const int h   = tid & (H_ - 1);
    const int b   = (tid >> 12) & (B_ - 1);
    const int seg = tid >> 14;
    const int s0  = seg * SEG;
    const int sw  = (seg == 0) ? 0 : s0 - WARM;
    const int nst = s0 + SEG - sw;                    // 128 or 176 (both %16==0)
    const float K2  = 2.885390082f;                   // 2*log2(e)
    const float gk  = gamma[h] * K2;
    const float bek = beta[h]  * K2;
    float state = 0.f;

    size_t idx = ((size_t)b * S_ + sw) * H_ + h;
    float cur[16], nxt[16];
    #pragma unroll
    for (int k = 0; k < 16; ++k) cur[k] = bf2f(u[idx + (size_t)k * H_]);

    int s = sw;
    const int ngroups = nst >> 4;
    for (int g = 0; g < ngroups; ++g) {
        const size_t nidx = idx + (size_t)16 * H_;
        if (g + 1 < ngroups) {
            #pragma unroll
            for (int k = 0; k < 16; ++k) nxt[k] = bf2f(u[nidx + (size_t)k * H_]);
        }
        #pragma unroll
        for (int k = 0; k < 16; ++k) {
            const float c = fmaf(cur[k], K2, bek);    // off-chain
            const float t = fmaf(state, gk, c);       // chain: fma
            const float e = fast_exp2(t);             // chain: v_exp_f32
            const float rr = fast_rcp(1.0f + e);      // chain: add + v_rcp_f32
            state = fmaf(-2.0f, rr, 1.0f);            // chain: fma
            if (s + k >= s0) st[idx + (size_t)k * H_] = f2bf(state);
        }
        idx = nidx; s += 16;
        #pragma unroll
        for (int k = 0; k < 16; ++k) cur[k] = nxt[k];
    }
}

extern "C" void kernel_launch(void* const* d_in, const int* in_sizes, int n_in,
                              void* d_out, int out_size, void* d_ws, size_t ws_size,
                              hipStream_t stream) {
    const float* x     = (const float*)d_in[0];  // [B,S,D]
    const float* W_in  = (const float*)d_in[1];  // [H,D]
    const float* b_in  = (const float*)d_in[2];  // [H]
    const float* W_out = (const float*)d_in[3];  // [D,H]
    const float* b_out = (const float*)d_in[4];  // [D]
    const float* gamma = (const float*)d_in[5];  // [H]
    const float* beta  = (const float*)d_in[6];  // [H]
    float* y = (float*)d_out;                    // [B,S,D] fp32

    // workspace layout (bf16 buffers), total ~192 MiB
    unsigned short* x_b    = (unsigned short*)d_ws;              // M*D
    unsigned short* win_b  = x_b    + (size_t)M_ * D_;           // H*D
    unsigned short* wout_b = win_b  + (size_t)H_ * D_;           // D*H
    unsigned short* u_b    = wout_b + (size_t)D_ * H_;           // M*H
    unsigned short* st_b   = u_b    + (size_t)M_ * H_;           // M*H

    // convert inputs to bf16
    cvt_f32_bf16<<<(M_ * D_) / 2048, 256, 0, stream>>>(x,     x_b,    M_ * D_);
    cvt_f32_bf16<<<(H_ * D_) / 2048, 256, 0, stream>>>(W_in,  win_b,  H_ * D_);
    cvt_f32_bf16<<<(D_ * H_) / 2048, 256, 0, stream>>>(W_out, wout_b, D_ * H_);

    // u = x @ W_in^T + b_in   -> bf16 [M,H]   grid: (cols, rows), 256x256 tiles
    dim3 g1(H_ / 256, M_ / 256);
    gemm_u<<<g1, 512, 0, stream>>>(x_b, win_b, b_in, u_b, M_, H_, D_);

    // segmented-parallel recurrence -> states bf16 [M,H]
    recur_seg<<<(P_ * B_ * H_) / 256, 256, 0, stream>>>(u_b, gamma, beta, st_b);

    // y = states @ W_out^T + b_out -> fp32 [M,D]   grid: (cols, rows)
    dim3 g2(D_ / 256, M_ / 256);
    gemm_y<<<g2, 512, 0, stream>>>(st_b, wout_b, b_out, y, M_, D_, H_);
}